// Round 3
// baseline (3245.989 us; speedup 1.0000x reference)
//
#include <hip/hip_runtime.h>

typedef __attribute__((ext_vector_type(8))) _Float16 v8h;
typedef __attribute__((ext_vector_type(4))) float v4f;

#define DEV __device__ __forceinline__

constexpr int S_ = 64;
constexpr int B_ = 256;
constexpr int E_ = 131072;
constexpr int T_ = S_ * B_;   // 16384

DEV float sigm(float x) { return 1.f / (1.f + __expf(-x)); }
DEV float tanh_f(float x) { return 1.f - 2.f / (__expf(2.f * x) + 1.f); }

// ---------------- weight fp32 -> fp16 (hi, optional lo residual) ----------------
struct CJob { const float* s; _Float16* d; _Float16* dlo; int n; int rowLen; int stride; };
struct CJobs { CJob j[9]; };

__global__ __launch_bounds__(256) void convert_k(CJobs jobs) {
  for (int q = 0; q < 9; ++q) {
    CJob jb = jobs.j[q];
    for (int i = blockIdx.x * 256 + threadIdx.x; i < jb.n; i += gridDim.x * 256) {
      int row = i / jb.rowLen;
      int col = i - row * jb.rowLen;
      float f = jb.s[(long)row * jb.stride + col];
      _Float16 hi = (_Float16)f;
      jb.d[i] = hi;
      if (jb.dlo) jb.dlo[i] = (_Float16)(f - (float)hi);
    }
  }
}

// ---------------- node embedding gather (fp32 table -> fp32) ----------------
__global__ __launch_bounds__(256) void embed_k(const int* __restrict__ nt,
                                               const float* __restrict__ tab,
                                               float* __restrict__ x0) {
  int t = blockIdx.x, j = threadIdx.x;
  x0[(long)t * 256 + j] = tab[nt[t] * 256 + j];
}

// ---------------- per-edge-type bias: pe[16][256] = edge_table @ W_e^T + bmsg (fp32 exact) ----------------
__global__ __launch_bounds__(256) void pe_k(const float* __restrict__ etab,
                                            const float* __restrict__ Wmsg,
                                            const float* __restrict__ bmsg,
                                            float* __restrict__ pe) {
  int j = threadIdx.x;
  const float* w = Wmsg + (long)j * 512 + 256;  // W_e = Wmsg[:, 256:512]
  for (int r = 0; r < 16; ++r) {
    float acc = bmsg[j];
    const float* e = etab + r * 256;
    for (int k = 0; k < 256; ++k) acc += e[k] * w[k];
    pe[r * 256 + j] = acc;
  }
}

// ---------------- CSR build (by dst) ----------------
__global__ __launch_bounds__(256) void count_k(const int* __restrict__ dst, int* __restrict__ cnt) {
  int e = blockIdx.x * 256 + threadIdx.x;
  if (e < E_) atomicAdd(&cnt[dst[e]], 1);
}

__global__ __launch_bounds__(256) void csr_scan_k(const int* __restrict__ cnt,
                                                  int* __restrict__ rowptr,
                                                  int* __restrict__ cur) {
  __shared__ int ps[256];
  int tid = threadIdx.x;
  int base = tid * 64;
  int s = 0;
  for (int i = 0; i < 64; ++i) s += cnt[base + i];
  ps[tid] = s;
  __syncthreads();
  for (int d = 1; d < 256; d <<= 1) {
    int v = (tid >= d) ? ps[tid - d] : 0;
    __syncthreads();
    ps[tid] += v;
    __syncthreads();
  }
  int run = (tid == 0) ? 0 : ps[tid - 1];
  for (int i = 0; i < 64; ++i) {
    rowptr[base + i] = run;
    cur[base + i] = run;
    run += cnt[base + i];
  }
  if (tid == 255) rowptr[T_] = run;
}

__global__ __launch_bounds__(256) void fill_k(const int* __restrict__ dst,
                                              int* __restrict__ cur,
                                              int* __restrict__ eord) {
  int e = blockIdx.x * 256 + threadIdx.x;
  if (e < E_) {
    int p = atomicAdd(&cur[dst[e]], 1);
    eord[p] = e;
  }
}

// ---------------- MFMA GEMM: C[M,N] = A[M,K]_fp32 @ W[N,K]^T (+bias) ----------------
// A split on the fly into fp16 hi+lo; W fp16 hi (+lo if WLO).
// 3-term: a_hi*w_hi + a_lo*w_hi + a_hi*w_lo  ->  ~fp32-equivalent.
template <int WLO, int C32, int BIAS>
__global__ __launch_bounds__(256) void gemm_nt(const float* __restrict__ Ap,
                                               const _Float16* __restrict__ Wp,
                                               const _Float16* __restrict__ Wlp,
                                               const float* __restrict__ bias,
                                               void* __restrict__ Cp,
                                               int M, int N, int K,
                                               long sA, long sW, long sB, long sC) {
  __shared__ _Float16 As[64][40];
  __shared__ _Float16 Al[64][40];
  __shared__ _Float16 Bs[64][40];
  __shared__ _Float16 Bl[64][40];
  const int bz = blockIdx.z;
  const int m0 = blockIdx.x * 64, n0 = blockIdx.y * 64;
  const int tid = threadIdx.x, lane = tid & 63, wv = tid >> 6;
  const int wy = wv >> 1, wx = wv & 1;
  const int sr = tid >> 2, skc = tid & 3;
  const _Float16* W = Wp + bz * sW;
  const float* A = Ap + bz * sA;
  v4f z4 = {0.f, 0.f, 0.f, 0.f};
  v4f acc[2][2];
  acc[0][0] = z4; acc[0][1] = z4; acc[1][0] = z4; acc[1][1] = z4;

  for (int k0 = 0; k0 < K; k0 += 32) {
    {
      const float* p = A + (long)(m0 + sr) * K + k0 + skc * 8;
      v4f f0 = *(const v4f*)p;
      v4f f1 = *(const v4f*)(p + 4);
      v8h hv, lv;
#pragma unroll
      for (int j = 0; j < 4; ++j) {
        hv[j] = (_Float16)f0[j]; lv[j] = (_Float16)(f0[j] - (float)hv[j]);
        hv[4 + j] = (_Float16)f1[j]; lv[4 + j] = (_Float16)(f1[j] - (float)hv[4 + j]);
      }
      *(v8h*)&As[sr][skc * 8] = hv;
      *(v8h*)&Al[sr][skc * 8] = lv;
    }
    *(v8h*)&Bs[sr][skc * 8] = *(const v8h*)(W + (long)(n0 + sr) * K + k0 + skc * 8);
    if constexpr (WLO)
      *(v8h*)&Bl[sr][skc * 8] = *(const v8h*)(Wlp + bz * sW + (long)(n0 + sr) * K + k0 + skc * 8);
    __syncthreads();
    const int fr = lane & 15, fk = (lane >> 4) * 8;
    v8h ah[2], alr[2], bh[2], blr[2];
    ah[0] = *(v8h*)&As[wy * 32 + fr][fk];
    ah[1] = *(v8h*)&As[wy * 32 + 16 + fr][fk];
    bh[0] = *(v8h*)&Bs[wx * 32 + fr][fk];
    bh[1] = *(v8h*)&Bs[wx * 32 + 16 + fr][fk];
    alr[0] = *(v8h*)&Al[wy * 32 + fr][fk];
    alr[1] = *(v8h*)&Al[wy * 32 + 16 + fr][fk];
    if constexpr (WLO) {
      blr[0] = *(v8h*)&Bl[wx * 32 + fr][fk];
      blr[1] = *(v8h*)&Bl[wx * 32 + 16 + fr][fk];
    }
#pragma unroll
    for (int mi = 0; mi < 2; ++mi)
#pragma unroll
      for (int ni = 0; ni < 2; ++ni) {
        acc[mi][ni] = __builtin_amdgcn_mfma_f32_16x16x32_f16(ah[mi], bh[ni], acc[mi][ni], 0, 0, 0);
        acc[mi][ni] = __builtin_amdgcn_mfma_f32_16x16x32_f16(alr[mi], bh[ni], acc[mi][ni], 0, 0, 0);
        if constexpr (WLO)
          acc[mi][ni] = __builtin_amdgcn_mfma_f32_16x16x32_f16(ah[mi], blr[ni], acc[mi][ni], 0, 0, 0);
      }
    __syncthreads();
  }
  const int fr = lane & 15, fq = lane >> 4;
#pragma unroll
  for (int mi = 0; mi < 2; ++mi)
#pragma unroll
    for (int ni = 0; ni < 2; ++ni)
#pragma unroll
      for (int j = 0; j < 4; ++j) {
        int row = m0 + wy * 32 + mi * 16 + fq * 4 + j;
        int col = n0 + wx * 32 + ni * 16 + fr;
        float v = acc[mi][ni][j];
        if (BIAS) v += bias[bz * sB + col];
        if (C32)
          ((float*)Cp)[bz * sC + (long)row * N + col] = v;
        else
          ((_Float16*)Cp)[bz * sC + (long)row * N + col] = (_Float16)v;
      }
}

// ---------------- recurrent GRU layer (both directions), batch-partitioned ----------------
// Block owns 16 batch rows of one direction, loops 64 timesteps.
// h fp32 in registers; fp16 hi+lo ping-pong in LDS feeds MFMA (~fp32 A precision).
// Whh in fp16 (2^-11 systematic error, 8x better than bf16) streamed from L2.
__global__ __launch_bounds__(256) void gru_layer_k(const float* __restrict__ gi,      // (2,T,768) fp32, bih included
                                                   const _Float16* __restrict__ Whh,  // (2,768,256) fp16
                                                   const float* __restrict__ bhh,     // (2,768)
                                                   float* __restrict__ y,             // (T,512) fp32
                                                   float* __restrict__ hfinal) {      // (2,256,256) fp32
  __shared__ _Float16 hbh[2][16][264];
  __shared__ _Float16 hbl[2][16][264];
  __shared__ float bh[768];
  const int dir = blockIdx.y;
  const int r0 = blockIdx.x * 16;
  const int tid = threadIdx.x, lane = tid & 63, w = tid >> 6;
  const int fr = lane & 15, fq = lane >> 4;
  const _Float16* Wd = Whh + (long)dir * 768 * 256;
  const float* gid = gi + (long)dir * T_ * 768;
  for (int i = tid; i < 2 * 16 * 264; i += 256) { ((_Float16*)hbh)[i] = (_Float16)0.f; ((_Float16*)hbl)[i] = (_Float16)0.f; }
  for (int i = tid; i < 768; i += 256) bh[i] = bhh[(long)dir * 768 + i];
  float hreg[4][4];
#pragma unroll
  for (int a = 0; a < 4; ++a)
#pragma unroll
    for (int b = 0; b < 4; ++b) hreg[a][b] = 0.f;
  __syncthreads();
  int p = 0;
  for (int step = 0; step < 64; ++step) {
    const int t = dir ? 63 - step : step;
    v8h a[8], al[8];
#pragma unroll
    for (int kc = 0; kc < 8; ++kc) {
      a[kc] = *(const v8h*)&hbh[p][fr][kc * 32 + fq * 8];
      al[kc] = *(const v8h*)&hbl[p][fr][kc * 32 + fq * 8];
    }
    v4f acc[3][4];
#pragma unroll
    for (int g = 0; g < 3; ++g)
#pragma unroll
      for (int ht = 0; ht < 4; ++ht) {
        v4f c = {0.f, 0.f, 0.f, 0.f};
        const _Float16* wr = Wd + (long)(g * 256 + w * 64 + ht * 16 + fr) * 256 + fq * 8;
#pragma unroll
        for (int kc = 0; kc < 8; ++kc) {
          v8h wvv = *(const v8h*)(wr + kc * 32);
          c = __builtin_amdgcn_mfma_f32_16x16x32_f16(a[kc], wvv, c, 0, 0, 0);
          c = __builtin_amdgcn_mfma_f32_16x16x32_f16(al[kc], wvv, c, 0, 0, 0);
        }
        acc[g][ht] = c;
      }
#pragma unroll
    for (int ht = 0; ht < 4; ++ht) {
      const int col = w * 64 + ht * 16 + fr;
      const float bhr = bh[col], bhz = bh[col + 256], bhn = bh[col + 512];
#pragma unroll
      for (int j = 0; j < 4; ++j) {
        const int row = fq * 4 + j;
        const float* gp = gid + ((long)t * 256 + r0 + row) * 768;
        float rr = sigm(gp[col] + acc[0][ht][j] + bhr);
        float zz = sigm(gp[col + 256] + acc[1][ht][j] + bhz);
        float hn = acc[2][ht][j] + bhn;
        float nn = tanh_f(gp[col + 512] + rr * hn);
        float hnew = (1.f - zz) * nn + zz * hreg[ht][j];
        hreg[ht][j] = hnew;
        _Float16 hv = (_Float16)hnew;
        hbh[p ^ 1][row][col] = hv;
        hbl[p ^ 1][row][col] = (_Float16)(hnew - (float)hv);
        y[((long)t * 256 + r0 + row) * 512 + (long)dir * 256 + col] = hnew;
      }
    }
    __syncthreads();
    p ^= 1;
  }
#pragma unroll
  for (int ht = 0; ht < 4; ++ht)
#pragma unroll
    for (int j = 0; j < 4; ++j)
      hfinal[((long)dir * 256 + r0 + fq * 4 + j) * 256 + w * 64 + ht * 16 + fr] = hreg[ht][j];
}

// ---------------- seq-major -> node-major permutation (fp32 rows of 512) ----------------
__global__ __launch_bounds__(256) void permgather_k(const float* __restrict__ inp, float* __restrict__ nb) {
  int t = blockIdx.x, tid = threadIdx.x;
  const float* s = inp + ((long)(t & 63) * 256 + (t >> 6)) * 512;
  float* d = nb + (long)t * 512;
  d[tid] = s[tid];
  d[tid + 256] = s[tid + 256];
}

// ---------------- CSR aggregation: agg[v] = sum_{e: dst=v} P[src[e]] + pe[et[e]] ----------------
__global__ __launch_bounds__(256) void aggregate_k(const int* __restrict__ rowptr,
                                                   const int* __restrict__ eord,
                                                   const int* __restrict__ src,
                                                   const int* __restrict__ et,
                                                   const float* __restrict__ P,
                                                   const float* __restrict__ pe,
                                                   float* __restrict__ agg) {
  int v = blockIdx.x * 4 + (threadIdx.x >> 6);
  int lane = threadIdx.x & 63;
  int b0 = rowptr[v], b1 = rowptr[v + 1];
  v4f acc = {0.f, 0.f, 0.f, 0.f};
  for (int i = b0; i < b1; ++i) {
    int e = eord[i];
    int s = src[e], ty = et[e];
    v4f pv = *(const v4f*)(P + (long)s * 256 + lane * 4);
    v4f ev = *(const v4f*)(pe + ty * 256 + lane * 4);
    acc += pv + ev;
  }
  *(v4f*)(agg + (long)v * 256 + lane * 4) = acc;
}

// ---------------- GRU cell elementwise (biases already in gi2/gh2) ----------------
__global__ __launch_bounds__(256) void cell_ew_k(const float* __restrict__ gi2,
                                                 const float* __restrict__ gh2,
                                                 float* __restrict__ nodeh) {
  int node = blockIdx.x, j = threadIdx.x;
  const float* a = gi2 + (long)node * 768;
  const float* b = gh2 + (long)node * 768;
  float rr = sigm(a[j] + b[j]);
  float zz = sigm(a[j + 256] + b[j + 256]);
  float nn = tanh_f(a[j + 512] + rr * b[j + 512]);
  float h = nodeh[(long)node * 256 + j];
  nodeh[(long)node * 256 + j] = (1.f - zz) * nn + zz * h;
}

// ---------------- gated sum per graph (fp32 pre-activations) ----------------
__global__ __launch_bounds__(256) void graph_reduce_k(const float* __restrict__ gt,
                                                      const float* __restrict__ bgate,
                                                      const float* __restrict__ bemb,
                                                      float* __restrict__ ge) {
  int g = blockIdx.x, tid = threadIdx.x;
  for (int col = tid; col < 512; col += 256) {
    float bg = bgate[col], be = bemb[col];
    float acc = 0.f;
    for (int p = 0; p < 64; ++p) {
      const float* row = gt + ((long)g * 64 + p) * 1024;
      acc += sigm(row[col] + bg) * (row[512 + col] + be);
    }
    ge[(long)g * 512 + col] = acc;
  }
}

// ---------------- merged = [hf|hb|graph_emb] @ Wglob^T + bglob (fp32) ----------------
__global__ __launch_bounds__(256) void merged_k(const float* __restrict__ hfinal,
                                                const float* __restrict__ ge,
                                                const float* __restrict__ Wglob,
                                                const float* __restrict__ bglob,
                                                float* __restrict__ out) {
  __shared__ float vec[1024];
  int g = blockIdx.x, tid = threadIdx.x;
  vec[tid] = hfinal[(long)g * 256 + tid];
  vec[256 + tid] = hfinal[(long)65536 + g * 256 + tid];
  vec[512 + tid] = ge[(long)g * 512 + tid];
  vec[768 + tid] = ge[(long)g * 512 + 256 + tid];
  __syncthreads();
  const float* wr = Wglob + (long)tid * 1024;
  float acc = bglob[tid];
  for (int k = 0; k < 1024; ++k) acc += vec[k] * wr[k];
  out[(long)g * 256 + tid] = acc;
}

// =========================== host ===========================
extern "C" void kernel_launch(void* const* d_in, const int* in_sizes, int n_in,
                              void* d_out, int out_size, void* d_ws, size_t ws_size,
                              hipStream_t stream) {
  (void)in_sizes; (void)n_in; (void)out_size; (void)ws_size;
  const float* node_table = (const float*)d_in[0];
  const float* Wih_l0 = (const float*)d_in[1];
  const float* Wih_l12 = (const float*)d_in[2];
  const float* WhhF = (const float*)d_in[3];
  const float* bih = (const float*)d_in[4];
  const float* bhh = (const float*)d_in[5];
  const float* WmdF = (const float*)d_in[6];
  const float* bmd = (const float*)d_in[7];
  const float* edge_table = (const float*)d_in[8];
  const float* Wmsg = (const float*)d_in[9];
  const float* bmsg = (const float*)d_in[10];
  const float* cWih = (const float*)d_in[11];
  const float* cWhh = (const float*)d_in[12];
  const float* cbih = (const float*)d_in[13];
  const float* cbhh = (const float*)d_in[14];
  const float* Wgate = (const float*)d_in[15];
  const float* bgate = (const float*)d_in[16];
  const float* Wemb = (const float*)d_in[17];
  const float* bemb = (const float*)d_in[18];
  const float* Wglob = (const float*)d_in[19];
  const float* bglob = (const float*)d_in[20];
  const int* node_types = (const int*)d_in[21];
  const int* edge_types = (const int*)d_in[22];
  const int* srcI = (const int*)d_in[23];
  const int* dstI = (const int*)d_in[24];

  float* node_h = (float*)d_out;                  // (T,256) = output 0, used as working buffer
  float* merged = (float*)d_out + (long)T_ * 256; // (256,256) = output 1

  char* w = (char*)d_ws;
  size_t off = 0;
  auto alloc = [&](size_t bytes) -> char* {
    char* ptr = w + off;
    off = (off + bytes + 255) & ~(size_t)255;
    return ptr;
  };
  _Float16* wWih0H = (_Float16*)alloc((size_t)2 * 768 * 256 * 2);
  _Float16* wWih0L = (_Float16*)alloc((size_t)2 * 768 * 256 * 2);
  _Float16* wWih12H = (_Float16*)alloc((size_t)2 * 2 * 768 * 512 * 2);
  _Float16* wWih12L = (_Float16*)alloc((size_t)2 * 2 * 768 * 512 * 2);
  _Float16* wWhh = (_Float16*)alloc((size_t)3 * 2 * 768 * 256 * 2);
  _Float16* wWmdH = (_Float16*)alloc((size_t)256 * 512 * 2);
  _Float16* wWmdL = (_Float16*)alloc((size_t)256 * 512 * 2);
  _Float16* wWxH = (_Float16*)alloc((size_t)256 * 256 * 2);
  _Float16* wWxL = (_Float16*)alloc((size_t)256 * 256 * 2);
  _Float16* wCWihH = (_Float16*)alloc((size_t)768 * 256 * 2);
  _Float16* wCWihL = (_Float16*)alloc((size_t)768 * 256 * 2);
  _Float16* wCWhhH = (_Float16*)alloc((size_t)768 * 256 * 2);
  _Float16* wCWhhL = (_Float16*)alloc((size_t)768 * 256 * 2);
  _Float16* wWcatH = (_Float16*)alloc((size_t)1024 * 256 * 2);
  _Float16* wWcatL = (_Float16*)alloc((size_t)1024 * 256 * 2);
  float* inpA = (float*)alloc((size_t)T_ * 512 * 4);
  float* inpB = (float*)alloc((size_t)T_ * 512 * 4);
  float* agg = (float*)alloc((size_t)T_ * 256 * 4);
  float* hfinal = (float*)alloc((size_t)2 * 256 * 256 * 4);
  float* pe = (float*)alloc((size_t)16 * 256 * 4);
  int* cnt = (int*)alloc((size_t)T_ * 4);
  int* rowptr = (int*)alloc((size_t)(T_ + 1) * 4);
  int* cur = (int*)alloc((size_t)T_ * 4);
  int* eord = (int*)alloc((size_t)E_ * 4);
  float* gemb = (float*)alloc((size_t)256 * 512 * 4);
  // Union region, 112 MB: phases do not overlap in time.
  //   GRU phase:  gi (2,T,768) fp32 = 96 MB @ +0 ; x0 (T,256) fp32 = 16 MB @ +96M
  //   MP phase:   Pbuf (T,256) = 16 MB @ +0 ; gi2 (T,768) = 48 MB @ +16M ; gh2 @ +64M
  //   epilogue:   gated (T,1024) fp32 = 64 MB @ +0
  char* R = alloc((size_t)112 * 1024 * 1024);
  float* gi = (float*)R;
  float* x0 = (float*)(R + (size_t)96 * 1024 * 1024);
  float* Pbuf = (float*)R;
  float* gi2 = (float*)(R + (size_t)16 * 1024 * 1024);
  float* gh2 = (float*)(R + (size_t)64 * 1024 * 1024);
  float* gatedF = (float*)R;

  // 1. weights -> fp16 hi (+ lo residual where W-systematic error matters downstream)
  CJobs jobs;
  jobs.j[0] = {Wih_l0, wWih0H, wWih0L, 2 * 768 * 256, 2 * 768 * 256, 2 * 768 * 256};
  jobs.j[1] = {Wih_l12, wWih12H, wWih12L, 2 * 2 * 768 * 512, 2 * 2 * 768 * 512, 2 * 2 * 768 * 512};
  jobs.j[2] = {WhhF, wWhh, nullptr, 3 * 2 * 768 * 256, 3 * 2 * 768 * 256, 3 * 2 * 768 * 256};
  jobs.j[3] = {WmdF, wWmdH, wWmdL, 256 * 512, 256 * 512, 256 * 512};
  jobs.j[4] = {Wmsg, wWxH, wWxL, 256 * 256, 256, 512};  // W_x = Wmsg[:, :256]
  jobs.j[5] = {cWih, wCWihH, wCWihL, 768 * 256, 768 * 256, 768 * 256};
  jobs.j[6] = {cWhh, wCWhhH, wCWhhL, 768 * 256, 768 * 256, 768 * 256};
  jobs.j[7] = {Wgate, wWcatH, wWcatL, 512 * 256, 512 * 256, 512 * 256};
  jobs.j[8] = {Wemb, wWcatH + 512 * 256, wWcatL + 512 * 256, 512 * 256, 512 * 256, 512 * 256};
  convert_k<<<1024, 256, 0, stream>>>(jobs);

  // 2. embeddings, edge-type bias, CSR
  embed_k<<<T_, 256, 0, stream>>>(node_types, node_table, x0);
  pe_k<<<1, 256, 0, stream>>>(edge_table, Wmsg, bmsg, pe);
  hipMemsetAsync(cnt, 0, (size_t)T_ * 4, stream);
  count_k<<<E_ / 256, 256, 0, stream>>>(dstI, cnt);
  csr_scan_k<<<1, 256, 0, stream>>>(cnt, rowptr, cur);
  fill_k<<<E_ / 256, 256, 0, stream>>>(dstI, cur, eord);

  // 3. three bidirectional GRU layers (gi fp32 via 3-term split GEMM; h hi+lo fp16)
  const float* inCur = x0;
  float* outBuf[3] = {inpA, inpB, inpA};
  int Kin = 256;
  for (int l = 0; l < 3; ++l) {
    const _Float16 *WlH, *WlL;
    long sW;
    if (l == 0) { WlH = wWih0H; WlL = wWih0L; sW = (long)768 * 256; }
    else {
      WlH = wWih12H + (size_t)(l - 1) * 2 * 768 * 512;
      WlL = wWih12L + (size_t)(l - 1) * 2 * 768 * 512;
      sW = (long)768 * 512;
    }
    gemm_nt<1, 1, 1><<<dim3(T_ / 64, 12, 2), 256, 0, stream>>>(
        inCur, WlH, WlL, bih + (long)l * 2 * 768, gi, T_, 768, Kin, 0L, sW, 768L, (long)T_ * 768);
    gru_layer_k<<<dim3(16, 2), 256, 0, stream>>>(
        gi, wWhh + (size_t)l * 2 * 768 * 256, bhh + (long)l * 2 * 768, outBuf[l], hfinal);
    inCur = outBuf[l];
    Kin = 512;
  }

  // 4. permute seq-major -> node-major; node_h = node_bidir @ Wmd^T + bmd
  permgather_k<<<T_, 256, 0, stream>>>(inpA, inpB);
  gemm_nt<1, 1, 1><<<dim3(T_ / 64, 4, 1), 256, 0, stream>>>(
      inpB, wWmdH, wWmdL, bmd, node_h, T_, 256, 512, 0L, 0L, 0L, 0L);

  // 5. message passing x3 (3-term split GEMMs: ~fp32 precision)
  for (int it = 0; it < 3; ++it) {
    gemm_nt<1, 1, 0><<<dim3(T_ / 64, 4, 1), 256, 0, stream>>>(
        node_h, wWxH, wWxL, nullptr, Pbuf, T_, 256, 256, 0L, 0L, 0L, 0L);
    aggregate_k<<<T_ / 4, 256, 0, stream>>>(rowptr, eord, srcI, edge_types, Pbuf, pe, agg);
    gemm_nt<1, 1, 1><<<dim3(T_ / 64, 12, 1), 256, 0, stream>>>(
        agg, wCWihH, wCWihL, cbih, gi2, T_, 768, 256, 0L, 0L, 0L, 0L);
    gemm_nt<1, 1, 1><<<dim3(T_ / 64, 12, 1), 256, 0, stream>>>(
        node_h, wCWhhH, wCWhhL, cbhh, gh2, T_, 768, 256, 0L, 0L, 0L, 0L);
    cell_ew_k<<<T_, 256, 0, stream>>>(gi2, gh2, node_h);
  }

  // 6. gated projections (3-term, fp32 out) + per-graph sum + merged
  gemm_nt<1, 1, 0><<<dim3(T_ / 64, 16, 1), 256, 0, stream>>>(
      node_h, wWcatH, wWcatL, nullptr, gatedF, T_, 1024, 256, 0L, 0L, 0L, 0L);
  graph_reduce_k<<<256, 256, 0, stream>>>(gatedF, bgate, bemb, gemb);
  merged_k<<<256, 256, 0, stream>>>(hfinal, gemb, Wglob, bglob, merged);
}